// Round 5
// baseline (878.530 us; speedup 1.0000x reference)
//
#include <hip/hip_runtime.h>

// AdderNet LeNet forward on MI355X — round 5.
// R4 finding: bank-conflict fix (2.47e7 -> 1.66e5) bought only 5% -> kernel is
// latency/occupancy-bound (true VALU ~28%, 3 waves/SIMD, 1 block/CU @ 100KB LDS).
// R5 change: split layer2 into 2 blocks per batch element (row halves 0-11 /
// 12-23). LDS/block = 32c x 16rows x 28 x 4B = 57.3KB -> 2 blocks/CU ->
// 6 waves/SIMD (2x). Per-thread: 12 cols (acc[12], xw[16]) -> ~68 VGPR,
// headroom for LDS-read pipelining. Col-octet pool straddle fixed via
// __shfl_xor(32) (h-partners in same wave); row-octet pool + FC head moved
// to a small pool_fc kernel via grm partials in ws.

// wt1: [5][5][32]  = [kh][kw][o]
// wt2: [32][5][5][32] = [c][kh][kw][o]
__global__ void prep_weights(const float* __restrict__ w1,
                             const float* __restrict__ w2,
                             float* __restrict__ wt1,
                             float* __restrict__ wt2) {
    int tid = threadIdx.x + blockIdx.x * blockDim.x;
    int stride = blockDim.x * gridDim.x;
    for (int i = tid; i < 5 * 5 * 32; i += stride) {
        int o = i & 31, kw = (i >> 5) % 5, kh = i / 160;
        wt1[i] = w1[o * 25 + kh * 5 + kw];
    }
    for (int i = tid; i < 32 * 5 * 5 * 32; i += stride) {
        int o = i & 31, kw = (i >> 5) % 5, kh = ((i >> 5) / 5) % 5, c = i / 800;
        wt2[i] = w2[o * 800 + c * 25 + kh * 5 + kw];
    }
}

// ---------------- layer 1 ----------------
// block = one batch element; 896 threads: o = tid&31, r = tid>>5 (0..27).
// r<26 compute h1 row r -> padded row r+2; r=26,27 write zero pad rows 0,1.
__global__ __launch_bounds__(896) void layer1(const float* __restrict__ x,
                                              const float* __restrict__ wt1,
                                              const float* __restrict__ a1v,
                                              float* __restrict__ h1pad) {
    __shared__ float lx[32 * 32];  // x[b] padded by 2 (orig -2..29)
    const int b = blockIdx.x;
    const int tid = threadIdx.x;

    for (int i = tid; i < 32 * 32; i += 896) {
        int pr = i >> 5, pc = i & 31;
        int r = pr - 2, c = pc - 2;
        float v = 0.f;
        if (r >= 0 && r < 28 && c >= 0 && c < 28) v = x[b * 784 + r * 28 + c];
        lx[i] = v;
    }
    __syncthreads();

    const int o = tid & 31, r = tid >> 5;
    float* orow = h1pad + (size_t)(b * 32 + o) * 784;

    if (r >= 26) {
        float4 z = {0.f, 0.f, 0.f, 0.f};
        float4* dst = (float4*)(orow + (r - 26) * 28);
#pragma unroll
        for (int i = 0; i < 7; i++) dst[i] = z;
        return;
    }

    float wv[25];
    const float* wp = wt1 + o;
#pragma unroll
    for (int k = 0; k < 25; k++) wv[k] = wp[k * 32];

    float acc[26];
#pragma unroll
    for (int j = 0; j < 26; j++) acc[j] = 0.f;

#pragma unroll
    for (int kh = 0; kh < 5; kh++) {
        const float4* xr = (const float4*)&lx[(r + kh) * 32];
        float xw[32];
#pragma unroll
        for (int i = 0; i < 8; i++) {
            float4 v = xr[i];
            xw[4 * i + 0] = v.x; xw[4 * i + 1] = v.y;
            xw[4 * i + 2] = v.z; xw[4 * i + 3] = v.w;
        }
#pragma unroll
        for (int kw = 0; kw < 5; kw++)
#pragma unroll
            for (int j = 0; j < 26; j++)
                acc[j] += fabsf(xw[j + kw] - wv[kh * 5 + kw]);
    }

    const float alpha = a1v[0];
    float outv[28];
    outv[0] = 0.f; outv[1] = 0.f;
#pragma unroll
    for (int j = 0; j < 26; j++) {
        float v = -acc[j];
        outv[j + 2] = (v >= 0.f) ? v : alpha * v;
    }
    float4* dst = (float4*)(orow + (r + 2) * 28);
#pragma unroll
    for (int i = 0; i < 7; i++) {
        float4 v = {outv[4 * i], outv[4 * i + 1], outv[4 * i + 2], outv[4 * i + 3]};
        dst[i] = v;
    }
}

// ---------------- layer 2 conv (split in row halves) ----------------
// block = (b, half); 768 threads: o = tid&31, q = tid>>5, r = q>>1 (local
// row 0..11), h = q&1 (col half: cols 12h..12h+11).
// Writes per-row col-octet maxes (after PReLU) to grm[b][half][o][r][3].
__global__ __launch_bounds__(768, 6) void layer2_conv(
    const float* __restrict__ h1pad, const float* __restrict__ wt2,
    const float* __restrict__ a2v, float* __restrict__ grm) {
    __shared__ float lx[32 * 16 * 28];  // 57344 B: rows r0..r0+15 of each c

    const int bh = blockIdx.x;
    const int b = bh >> 1, half = bh & 1;
    const int tid = threadIdx.x;
    const int r0 = half * 12;

    {   // stage: per c, 16 rows x 28 cols = 112 float4 (16B-aligned: r0*28%4==0)
        const float4* src = (const float4*)(h1pad + (size_t)b * 25088 + r0 * 28);
        float4* dst = (float4*)lx;
        for (int i = tid; i < 3584; i += 768) {
            int c = i / 112, rem = i - c * 112;
            dst[c * 112 + rem] = src[c * 196 + rem];
        }
    }
    __syncthreads();

    const int o = tid & 31;
    const int q = tid >> 5;
    const int r = q >> 1;        // local row 0..11
    const int h = q & 1;         // col half
    const int colbase = 12 * h;

    float acc[12];
#pragma unroll
    for (int j = 0; j < 12; j++) acc[j] = 0.f;

    for (int c = 0; c < 32; c++) {
        float wv[25];
        const float* wp = wt2 + c * 800 + o;
#pragma unroll
        for (int k = 0; k < 25; k++) wv[k] = wp[k * 32];

#pragma unroll
        for (int kh = 0; kh < 5; kh++) {
            const float4* xr = (const float4*)&lx[(c * 16 + r + kh) * 28 + colbase];
            float xw[16];
#pragma unroll
            for (int i = 0; i < 4; i++) {
                float4 v = xr[i];
                xw[4 * i + 0] = v.x; xw[4 * i + 1] = v.y;
                xw[4 * i + 2] = v.z; xw[4 * i + 3] = v.w;
            }
#pragma unroll
            for (int kw = 0; kw < 5; kw++)
#pragma unroll
                for (int j = 0; j < 12; j++)
                    acc[j] += fabsf(xw[j + kw] - wv[kh * 5 + kw]);
        }
    }

    // PReLU, then col-octet maxes. Octets: {0-7},{8-15},{16-23} global cols.
    // h=0 owns cols 0..11 (octet0 full + octet1 low), h=1 owns 12..23.
    const float alpha = a2v[0];
    float p[12];
#pragma unroll
    for (int j = 0; j < 12; j++) {
        float v = -acc[j];
        p[j] = (v >= 0.f) ? v : alpha * v;
    }
    float mFull, mEdge;
    if (h == 0) {
        mFull = p[0]; mEdge = p[8];
#pragma unroll
        for (int j = 1; j < 8; j++) mFull = fmaxf(mFull, p[j]);
#pragma unroll
        for (int j = 9; j < 12; j++) mEdge = fmaxf(mEdge, p[j]);
    } else {
        mEdge = p[0]; mFull = p[4];
#pragma unroll
        for (int j = 1; j < 4; j++) mEdge = fmaxf(mEdge, p[j]);
#pragma unroll
        for (int j = 5; j < 12; j++) mFull = fmaxf(mFull, p[j]);
    }
    // exchange octet-1 partials between h-partners (lanes L <-> L+32)
    float otherEdge = __shfl_xor(mEdge, 32);
    float mMid = fmaxf(mEdge, otherEdge);

    float* g = grm + ((size_t)(b * 2 + half) * 32 + o) * 36 + r * 3;
    if (h == 0) { g[0] = mFull; g[1] = mMid; }
    else        { g[2] = mFull; }
}

// ---------------- vertical pool + FC head ----------------
// block = one batch element; 320 threads (288 used for pooling, 64 for FC).
__global__ __launch_bounds__(320) void pool_fc(
    const float* __restrict__ grm, const float* __restrict__ ip1_w,
    const float* __restrict__ ip1_b, const float* __restrict__ a3v,
    const float* __restrict__ ip2_w, float* __restrict__ dout) {
    __shared__ float lpool[288];
    const int b = blockIdx.x, t = threadIdx.x;

    if (t < 288) {
        int oo = t / 9, rem = t % 9, ii = rem / 3, jj = rem % 3;
        float m = -1e30f;
#pragma unroll
        for (int k = 0; k < 8; k++) {
            int gr = 8 * ii + k;            // global row 0..23
            int hf = (gr >= 12) ? 1 : 0;
            int lr = gr - 12 * hf;
            m = fmaxf(m, grm[((size_t)(b * 2 + hf) * 32 + oo) * 36 + lr * 3 + jj]);
        }
        lpool[t] = m;  // t == oo*9 + ii*3 + jj
    }
    __syncthreads();

    if (t < 64) {
        float f0 = 0.f, f1 = 0.f;
        for (int i = t; i < 288; i += 64) {
            float p = lpool[i];
            f0 += p * ip1_w[i];
            f1 += p * ip1_w[288 + i];
        }
#pragma unroll
        for (int off = 32; off > 0; off >>= 1) {
            f0 += __shfl_down(f0, off);
            f1 += __shfl_down(f1, off);
        }
        if (t == 0) {
            float a3 = a3v[0];
            float i0 = f0 + ip1_b[0], i1 = f1 + ip1_b[1];
            i0 = (i0 >= 0.f) ? i0 : a3 * i0;
            i1 = (i1 >= 0.f) ? i1 : a3 * i1;
            dout[b * 2 + 0] = i0;
            dout[b * 2 + 1] = i1;
#pragma unroll
            for (int m = 0; m < 10; m++)
                dout[512 + b * 10 + m] = i0 * ip2_w[m * 2] + i1 * ip2_w[m * 2 + 1];
        }
    }
}

extern "C" void kernel_launch(void* const* d_in, const int* in_sizes, int n_in,
                              void* d_out, int out_size, void* d_ws, size_t ws_size,
                              hipStream_t stream) {
    const float* x     = (const float*)d_in[0];
    const float* w1    = (const float*)d_in[1];
    const float* a1    = (const float*)d_in[2];
    const float* w2    = (const float*)d_in[3];
    const float* a2    = (const float*)d_in[4];
    const float* ip1_w = (const float*)d_in[5];
    const float* ip1_b = (const float*)d_in[6];
    const float* a3    = (const float*)d_in[7];
    const float* ip2_w = (const float*)d_in[8];
    float* out = (float*)d_out;

    char* ws = (char*)d_ws;
    float* wt1   = (float*)(ws);                //    3200 B
    float* wt2   = (float*)(ws + 4096);         //  102400 B
    float* grm   = (float*)(ws + 131072);       // 2359296 B [256][2][32][12][3]
    float* h1pad = (float*)(ws + 4194304);      // 25.69 MB

    prep_weights<<<52, 512, 0, stream>>>(w1, w2, wt1, wt2);
    layer1<<<256, 896, 0, stream>>>(x, wt1, a1, h1pad);
    layer2_conv<<<512, 768, 0, stream>>>(h1pad, wt2, a2, grm);
    pool_fc<<<256, 320, 0, stream>>>(grm, ip1_w, ip1_b, a3, ip2_w, out);
}

// Round 9
// 314.379 us; speedup vs baseline: 2.7945x; 2.7945x over previous
//
#include <hip/hip_runtime.h>

// AdderNet LeNet forward on MI355X — round 6 build (4th submit; R6-R8 benches
// were infra acquisition timeouts, no data).
// R5 post-mortem: __launch_bounds__(768,6) capped VGPR at 40 (hipcc models a
// 256-reg/SIMD pool: 256/6->40) -> acc/xw/wv spilled to scratch -> +2.5GB
// HBM traffic (WRITE 1.13->2.61GB, FETCH 0.34->1.37GB) -> 814us, memory-bound.
// R6: same split structure, bounds (768,3) -> VGPR cap 80 (need ~70). HW then
// fits 2 blocks/CU (LDS 2x57.3KB=114.7KB <= 160KB; 512/72 >= 6 waves/SIMD)
// -> 24 waves/CU with NO spills. Clean test of the latency-hiding theory.

// wt1: [5][5][32]  = [kh][kw][o]
// wt2: [32][5][5][32] = [c][kh][kw][o]
__global__ void prep_weights(const float* __restrict__ w1,
                             const float* __restrict__ w2,
                             float* __restrict__ wt1,
                             float* __restrict__ wt2) {
    int tid = threadIdx.x + blockIdx.x * blockDim.x;
    int stride = blockDim.x * gridDim.x;
    for (int i = tid; i < 5 * 5 * 32; i += stride) {
        int o = i & 31, kw = (i >> 5) % 5, kh = i / 160;
        wt1[i] = w1[o * 25 + kh * 5 + kw];
    }
    for (int i = tid; i < 32 * 5 * 5 * 32; i += stride) {
        int o = i & 31, kw = (i >> 5) % 5, kh = ((i >> 5) / 5) % 5, c = i / 800;
        wt2[i] = w2[o * 800 + c * 25 + kh * 5 + kw];
    }
}

// ---------------- layer 1 ----------------
// block = one batch element; 896 threads: o = tid&31, r = tid>>5 (0..27).
// r<26 compute h1 row r -> padded row r+2; r=26,27 write zero pad rows 0,1.
__global__ __launch_bounds__(896) void layer1(const float* __restrict__ x,
                                              const float* __restrict__ wt1,
                                              const float* __restrict__ a1v,
                                              float* __restrict__ h1pad) {
    __shared__ float lx[32 * 32];  // x[b] padded by 2 (orig -2..29)
    const int b = blockIdx.x;
    const int tid = threadIdx.x;

    for (int i = tid; i < 32 * 32; i += 896) {
        int pr = i >> 5, pc = i & 31;
        int r = pr - 2, c = pc - 2;
        float v = 0.f;
        if (r >= 0 && r < 28 && c >= 0 && c < 28) v = x[b * 784 + r * 28 + c];
        lx[i] = v;
    }
    __syncthreads();

    const int o = tid & 31, r = tid >> 5;
    float* orow = h1pad + (size_t)(b * 32 + o) * 784;

    if (r >= 26) {
        float4 z = {0.f, 0.f, 0.f, 0.f};
        float4* dst = (float4*)(orow + (r - 26) * 28);
#pragma unroll
        for (int i = 0; i < 7; i++) dst[i] = z;
        return;
    }

    float wv[25];
    const float* wp = wt1 + o;
#pragma unroll
    for (int k = 0; k < 25; k++) wv[k] = wp[k * 32];

    float acc[26];
#pragma unroll
    for (int j = 0; j < 26; j++) acc[j] = 0.f;

#pragma unroll
    for (int kh = 0; kh < 5; kh++) {
        const float4* xr = (const float4*)&lx[(r + kh) * 32];
        float xw[32];
#pragma unroll
        for (int i = 0; i < 8; i++) {
            float4 v = xr[i];
            xw[4 * i + 0] = v.x; xw[4 * i + 1] = v.y;
            xw[4 * i + 2] = v.z; xw[4 * i + 3] = v.w;
        }
#pragma unroll
        for (int kw = 0; kw < 5; kw++)
#pragma unroll
            for (int j = 0; j < 26; j++)
                acc[j] += fabsf(xw[j + kw] - wv[kh * 5 + kw]);
    }

    const float alpha = a1v[0];
    float outv[28];
    outv[0] = 0.f; outv[1] = 0.f;
#pragma unroll
    for (int j = 0; j < 26; j++) {
        float v = -acc[j];
        outv[j + 2] = (v >= 0.f) ? v : alpha * v;
    }
    float4* dst = (float4*)(orow + (r + 2) * 28);
#pragma unroll
    for (int i = 0; i < 7; i++) {
        float4 v = {outv[4 * i], outv[4 * i + 1], outv[4 * i + 2], outv[4 * i + 3]};
        dst[i] = v;
    }
}

// ---------------- layer 2 conv (split in row halves) ----------------
// block = (b, half); 768 threads: o = tid&31, q = tid>>5, r = q>>1 (local
// row 0..11), h = q&1 (col half: cols 12h..12h+11).
// Writes per-row col-octet maxes (after PReLU) to grm[b][half][o][r][3].
__global__ __launch_bounds__(768, 3) void layer2_conv(
    const float* __restrict__ h1pad, const float* __restrict__ wt2,
    const float* __restrict__ a2v, float* __restrict__ grm) {
    __shared__ float lx[32 * 16 * 28];  // 57344 B: rows r0..r0+15 of each c

    const int bh = blockIdx.x;
    const int b = bh >> 1, half = bh & 1;
    const int tid = threadIdx.x;
    const int r0 = half * 12;

    {   // stage: per c, 16 rows x 28 cols = 112 float4 (16B-aligned: r0*28%4==0)
        const float4* src = (const float4*)(h1pad + (size_t)b * 25088 + r0 * 28);
        float4* dst = (float4*)lx;
        for (int i = tid; i < 3584; i += 768) {
            int c = i / 112, rem = i - c * 112;
            dst[c * 112 + rem] = src[c * 196 + rem];
        }
    }
    __syncthreads();

    const int o = tid & 31;
    const int q = tid >> 5;
    const int r = q >> 1;        // local row 0..11
    const int h = q & 1;         // col half
    const int colbase = 12 * h;

    float acc[12];
#pragma unroll
    for (int j = 0; j < 12; j++) acc[j] = 0.f;

    for (int c = 0; c < 32; c++) {
        float wv[25];
        const float* wp = wt2 + c * 800 + o;
#pragma unroll
        for (int k = 0; k < 25; k++) wv[k] = wp[k * 32];

#pragma unroll
        for (int kh = 0; kh < 5; kh++) {
            const float4* xr = (const float4*)&lx[(c * 16 + r + kh) * 28 + colbase];
            float xw[16];
#pragma unroll
            for (int i = 0; i < 4; i++) {
                float4 v = xr[i];
                xw[4 * i + 0] = v.x; xw[4 * i + 1] = v.y;
                xw[4 * i + 2] = v.z; xw[4 * i + 3] = v.w;
            }
#pragma unroll
            for (int kw = 0; kw < 5; kw++)
#pragma unroll
                for (int j = 0; j < 12; j++)
                    acc[j] += fabsf(xw[j + kw] - wv[kh * 5 + kw]);
        }
    }

    // PReLU, then col-octet maxes. Octets: {0-7},{8-15},{16-23} global cols.
    // h=0 owns cols 0..11 (octet0 full + octet1 low), h=1 owns 12..23.
    const float alpha = a2v[0];
    float p[12];
#pragma unroll
    for (int j = 0; j < 12; j++) {
        float v = -acc[j];
        p[j] = (v >= 0.f) ? v : alpha * v;
    }
    float mFull, mEdge;
    if (h == 0) {
        mFull = p[0]; mEdge = p[8];
#pragma unroll
        for (int j = 1; j < 8; j++) mFull = fmaxf(mFull, p[j]);
#pragma unroll
        for (int j = 9; j < 12; j++) mEdge = fmaxf(mEdge, p[j]);
    } else {
        mEdge = p[0]; mFull = p[4];
#pragma unroll
        for (int j = 1; j < 4; j++) mEdge = fmaxf(mEdge, p[j]);
#pragma unroll
        for (int j = 5; j < 12; j++) mFull = fmaxf(mFull, p[j]);
    }
    // exchange octet-1 partials between h-partners (lanes L <-> L+32)
    float otherEdge = __shfl_xor(mEdge, 32);
    float mMid = fmaxf(mEdge, otherEdge);

    float* g = grm + ((size_t)(b * 2 + half) * 32 + o) * 36 + r * 3;
    if (h == 0) { g[0] = mFull; g[1] = mMid; }
    else        { g[2] = mFull; }
}

// ---------------- vertical pool + FC head ----------------
// block = one batch element; 320 threads (288 used for pooling, 64 for FC).
__global__ __launch_bounds__(320) void pool_fc(
    const float* __restrict__ grm, const float* __restrict__ ip1_w,
    const float* __restrict__ ip1_b, const float* __restrict__ a3v,
    const float* __restrict__ ip2_w, float* __restrict__ dout) {
    __shared__ float lpool[288];
    const int b = blockIdx.x, t = threadIdx.x;

    if (t < 288) {
        int oo = t / 9, rem = t % 9, ii = rem / 3, jj = rem % 3;
        float m = -1e30f;
#pragma unroll
        for (int k = 0; k < 8; k++) {
            int gr = 8 * ii + k;            // global row 0..23
            int hf = (gr >= 12) ? 1 : 0;
            int lr = gr - 12 * hf;
            m = fmaxf(m, grm[((size_t)(b * 2 + hf) * 32 + oo) * 36 + lr * 3 + jj]);
        }
        lpool[t] = m;  // t == oo*9 + ii*3 + jj
    }
    __syncthreads();

    if (t < 64) {
        float f0 = 0.f, f1 = 0.f;
        for (int i = t; i < 288; i += 64) {
            float p = lpool[i];
            f0 += p * ip1_w[i];
            f1 += p * ip1_w[288 + i];
        }
#pragma unroll
        for (int off = 32; off > 0; off >>= 1) {
            f0 += __shfl_down(f0, off);
            f1 += __shfl_down(f1, off);
        }
        if (t == 0) {
            float a3 = a3v[0];
            float i0 = f0 + ip1_b[0], i1 = f1 + ip1_b[1];
            i0 = (i0 >= 0.f) ? i0 : a3 * i0;
            i1 = (i1 >= 0.f) ? i1 : a3 * i1;
            dout[b * 2 + 0] = i0;
            dout[b * 2 + 1] = i1;
#pragma unroll
            for (int m = 0; m < 10; m++)
                dout[512 + b * 10 + m] = i0 * ip2_w[m * 2] + i1 * ip2_w[m * 2 + 1];
        }
    }
}

extern "C" void kernel_launch(void* const* d_in, const int* in_sizes, int n_in,
                              void* d_out, int out_size, void* d_ws, size_t ws_size,
                              hipStream_t stream) {
    const float* x     = (const float*)d_in[0];
    const float* w1    = (const float*)d_in[1];
    const float* a1    = (const float*)d_in[2];
    const float* w2    = (const float*)d_in[3];
    const float* a2    = (const float*)d_in[4];
    const float* ip1_w = (const float*)d_in[5];
    const float* ip1_b = (const float*)d_in[6];
    const float* a3    = (const float*)d_in[7];
    const float* ip2_w = (const float*)d_in[8];
    float* out = (float*)d_out;

    char* ws = (char*)d_ws;
    float* wt1   = (float*)(ws);                //    3200 B
    float* wt2   = (float*)(ws + 4096);         //  102400 B
    float* grm   = (float*)(ws + 131072);       // 2359296 B [256][2][32][12][3]
    float* h1pad = (float*)(ws + 4194304);      // 25.69 MB

    prep_weights<<<52, 512, 0, stream>>>(w1, w2, wt1, wt2);
    layer1<<<256, 896, 0, stream>>>(x, wt1, a1, h1pad);
    layer2_conv<<<512, 768, 0, stream>>>(h1pad, wt2, a2, grm);
    pool_fc<<<256, 320, 0, stream>>>(grm, ip1_w, ip1_b, a3, ip2_w, out);
}

// Round 17
// 253.212 us; speedup vs baseline: 3.4695x; 1.2416x over previous
//
#include <hip/hip_runtime.h>
#include <hip/hip_fp16.h>

// AdderNet LeNet forward on MI355X — round 11 build (7th submit; R11-R16
// benches were infra acquisition timeouts). R10 fix: cvt_pkrtz returns
// __fp16-vector, not _Float16-vector; bit_cast via auto.
// R9: layer2 255.8us, VALUBusy 89%, dur*VALUBusy conserved across R2/R4/R9
// -> VALU-issue-bound. This build cuts the instruction count: fp16x2 packed
// math, pairing channels (c,c+1) per 32-bit reg:
//   v_pk_add_f16(sub,neg-mod) + packed-abs + v_pk_add_f16
// = 3 inst / 2 elements vs 4. Layer1/h1pad stay fp32; layer2's stage loop
// converts via v_cvt_pkrtz; weights pre-packed [cp][k][o] fp16x2.
// fp16 halves sum <=~1060 per 8-cp group, promoted to fp32 every 8 cp ->
// err ~6 RMS at ip1, threshold 26.56.

typedef unsigned int u32;

__device__ __forceinline__ __half2 bch2(u32 v) { return __builtin_bit_cast(__half2, v); }
__device__ __forceinline__ u32 bcu(__half2 v) { return __builtin_bit_cast(u32, v); }

// wt1: [5][5][32] f32 (layer1); wt2h: [16][25][32] u32 = fp16x2 {c=2cp, c=2cp+1}
__global__ void prep_weights(const float* __restrict__ w1,
                             const float* __restrict__ w2,
                             float* __restrict__ wt1,
                             u32* __restrict__ wt2h) {
    int tid = threadIdx.x + blockIdx.x * blockDim.x;
    int stride = blockDim.x * gridDim.x;
    for (int i = tid; i < 5 * 5 * 32; i += stride) {
        int o = i & 31, kw = (i >> 5) % 5, kh = i / 160;
        wt1[i] = w1[o * 25 + kh * 5 + kw];
    }
    for (int i = tid; i < 16 * 25 * 32; i += stride) {
        int o = i & 31, k = (i >> 5) % 25, cp = i / 800;
        __half lo = __float2half(w2[o * 800 + (2 * cp) * 25 + k]);
        __half hi = __float2half(w2[o * 800 + (2 * cp + 1) * 25 + k]);
        wt2h[i] = bcu(__halves2half2(lo, hi));
    }
}

// ---------------- layer 1 (unchanged from R6: fp32 out) ----------------
__global__ __launch_bounds__(896) void layer1(const float* __restrict__ x,
                                              const float* __restrict__ wt1,
                                              const float* __restrict__ a1v,
                                              float* __restrict__ h1pad) {
    __shared__ float lx[32 * 32];
    const int b = blockIdx.x;
    const int tid = threadIdx.x;

    for (int i = tid; i < 32 * 32; i += 896) {
        int pr = i >> 5, pc = i & 31;
        int r = pr - 2, c = pc - 2;
        float v = 0.f;
        if (r >= 0 && r < 28 && c >= 0 && c < 28) v = x[b * 784 + r * 28 + c];
        lx[i] = v;
    }
    __syncthreads();

    const int o = tid & 31, r = tid >> 5;
    float* orow = h1pad + (size_t)(b * 32 + o) * 784;

    if (r >= 26) {
        float4 z = {0.f, 0.f, 0.f, 0.f};
        float4* dst = (float4*)(orow + (r - 26) * 28);
#pragma unroll
        for (int i = 0; i < 7; i++) dst[i] = z;
        return;
    }

    float wv[25];
    const float* wp = wt1 + o;
#pragma unroll
    for (int k = 0; k < 25; k++) wv[k] = wp[k * 32];

    float acc[26];
#pragma unroll
    for (int j = 0; j < 26; j++) acc[j] = 0.f;

#pragma unroll
    for (int kh = 0; kh < 5; kh++) {
        const float4* xr = (const float4*)&lx[(r + kh) * 32];
        float xw[32];
#pragma unroll
        for (int i = 0; i < 8; i++) {
            float4 v = xr[i];
            xw[4 * i + 0] = v.x; xw[4 * i + 1] = v.y;
            xw[4 * i + 2] = v.z; xw[4 * i + 3] = v.w;
        }
#pragma unroll
        for (int kw = 0; kw < 5; kw++)
#pragma unroll
            for (int j = 0; j < 26; j++)
                acc[j] += fabsf(xw[j + kw] - wv[kh * 5 + kw]);
    }

    const float alpha = a1v[0];
    float outv[28];
    outv[0] = 0.f; outv[1] = 0.f;
#pragma unroll
    for (int j = 0; j < 26; j++) {
        float v = -acc[j];
        outv[j + 2] = (v >= 0.f) ? v : alpha * v;
    }
    float4* dst = (float4*)(orow + (r + 2) * 28);
#pragma unroll
    for (int i = 0; i < 7; i++) {
        float4 v = {outv[4 * i], outv[4 * i + 1], outv[4 * i + 2], outv[4 * i + 3]};
        dst[i] = v;
    }
}

// ---------------- layer 2 conv: fp16x2 channel-paired ----------------
// block = (b, half); 768 threads: o = tid&31, q = tid>>5, r = q>>1, h = q&1.
__global__ __launch_bounds__(768, 3) void layer2_conv(
    const float* __restrict__ h1pad, const u32* __restrict__ wt2h,
    const float* __restrict__ a2v, float* __restrict__ grm) {
    __shared__ u32 lx[16 * 16 * 28];  // 28672 B: [cp][lr 0..15][col 0..27] fp16x2

    const int bh = blockIdx.x;
    const int b = bh >> 1, half = bh & 1;
    const int tid = threadIdx.x;
    const int r0 = half * 12;

    {   // stage + fp32->fp16x2 convert: pair c-planes 2cp, 2cp+1
        const float4* src = (const float4*)h1pad + (size_t)b * 6272 + r0 * 7;
        uint4* dst = (uint4*)lx;
        for (int i = tid; i < 1792; i += 768) {
            int cp = i / 112, rem = i - cp * 112;   // rem = lr*7 + colgroup
            float4 a = src[cp * 392 + rem];         // plane c = 2cp
            float4 c2 = src[cp * 392 + 196 + rem];  // plane c = 2cp+1
            auto t0 = __builtin_amdgcn_cvt_pkrtz(a.x, c2.x);
            auto t1 = __builtin_amdgcn_cvt_pkrtz(a.y, c2.y);
            auto t2 = __builtin_amdgcn_cvt_pkrtz(a.z, c2.z);
            auto t3 = __builtin_amdgcn_cvt_pkrtz(a.w, c2.w);
            uint4 v;
            v.x = __builtin_bit_cast(u32, t0);
            v.y = __builtin_bit_cast(u32, t1);
            v.z = __builtin_bit_cast(u32, t2);
            v.w = __builtin_bit_cast(u32, t3);
            dst[cp * 112 + rem] = v;
        }
    }
    __syncthreads();

    const int o = tid & 31;
    const int q = tid >> 5;
    const int r = q >> 1;        // local row 0..11
    const int h = q & 1;         // col half
    const int colbase = 12 * h;

    __half2 accp[12];
    float facc[12];
#pragma unroll
    for (int j = 0; j < 12; j++) {
        accp[j] = __float2half2_rn(0.f);
        facc[j] = 0.f;
    }

    for (int g = 0; g < 2; g++) {
#pragma unroll 1
        for (int cp8 = 0; cp8 < 8; cp8++) {
            const int cp = g * 8 + cp8;
            u32 wv[25];
            const u32* wp = wt2h + cp * 800 + o;
#pragma unroll
            for (int k = 0; k < 25; k++) wv[k] = wp[k * 32];

#pragma unroll
            for (int kh = 0; kh < 5; kh++) {
                const uint4* xr = (const uint4*)&lx[(cp * 16 + r + kh) * 28 + colbase];
                u32 xw[16];
#pragma unroll
                for (int i = 0; i < 4; i++) {
                    uint4 v = xr[i];
                    xw[4 * i + 0] = v.x; xw[4 * i + 1] = v.y;
                    xw[4 * i + 2] = v.z; xw[4 * i + 3] = v.w;
                }
#pragma unroll
                for (int kw = 0; kw < 5; kw++) {
                    __half2 w = bch2(wv[kh * 5 + kw]);
#pragma unroll
                    for (int j = 0; j < 12; j++) {
                        __half2 xv = bch2(xw[j + kw]);
                        accp[j] = __hadd2(accp[j], __habs2(__hsub2(xv, w)));
                    }
                }
            }
        }
        // promote halves to fp32 every 8 cp (keeps fp16 partials <= ~1100)
#pragma unroll
        for (int j = 0; j < 12; j++) {
            facc[j] += __low2float(accp[j]) + __high2float(accp[j]);
            accp[j] = __float2half2_rn(0.f);
        }
    }

    // PReLU + col-octet maxes (identical structure to R6)
    const float alpha = a2v[0];
    float p[12];
#pragma unroll
    for (int j = 0; j < 12; j++) {
        float v = -facc[j];
        p[j] = (v >= 0.f) ? v : alpha * v;
    }
    float mFull, mEdge;
    if (h == 0) {
        mFull = p[0]; mEdge = p[8];
#pragma unroll
        for (int j = 1; j < 8; j++) mFull = fmaxf(mFull, p[j]);
#pragma unroll
        for (int j = 9; j < 12; j++) mEdge = fmaxf(mEdge, p[j]);
    } else {
        mEdge = p[0]; mFull = p[4];
#pragma unroll
        for (int j = 1; j < 4; j++) mEdge = fmaxf(mEdge, p[j]);
#pragma unroll
        for (int j = 5; j < 12; j++) mFull = fmaxf(mFull, p[j]);
    }
    float otherEdge = __shfl_xor(mEdge, 32);
    float mMid = fmaxf(mEdge, otherEdge);

    float* g = grm + ((size_t)(b * 2 + half) * 32 + o) * 36 + r * 3;
    if (h == 0) { g[0] = mFull; g[1] = mMid; }
    else        { g[2] = mFull; }
}

// ---------------- vertical pool + FC head (unchanged) ----------------
__global__ __launch_bounds__(320) void pool_fc(
    const float* __restrict__ grm, const float* __restrict__ ip1_w,
    const float* __restrict__ ip1_b, const float* __restrict__ a3v,
    const float* __restrict__ ip2_w, float* __restrict__ dout) {
    __shared__ float lpool[288];
    const int b = blockIdx.x, t = threadIdx.x;

    if (t < 288) {
        int oo = t / 9, rem = t % 9, ii = rem / 3, jj = rem % 3;
        float m = -1e30f;
#pragma unroll
        for (int k = 0; k < 8; k++) {
            int gr = 8 * ii + k;
            int hf = (gr >= 12) ? 1 : 0;
            int lr = gr - 12 * hf;
            m = fmaxf(m, grm[((size_t)(b * 2 + hf) * 32 + oo) * 36 + lr * 3 + jj]);
        }
        lpool[t] = m;
    }
    __syncthreads();

    if (t < 64) {
        float f0 = 0.f, f1 = 0.f;
        for (int i = t; i < 288; i += 64) {
            float p = lpool[i];
            f0 += p * ip1_w[i];
            f1 += p * ip1_w[288 + i];
        }
#pragma unroll
        for (int off = 32; off > 0; off >>= 1) {
            f0 += __shfl_down(f0, off);
            f1 += __shfl_down(f1, off);
        }
        if (t == 0) {
            float a3 = a3v[0];
            float i0 = f0 + ip1_b[0], i1 = f1 + ip1_b[1];
            i0 = (i0 >= 0.f) ? i0 : a3 * i0;
            i1 = (i1 >= 0.f) ? i1 : a3 * i1;
            dout[b * 2 + 0] = i0;
            dout[b * 2 + 1] = i1;
#pragma unroll
            for (int m = 0; m < 10; m++)
                dout[512 + b * 10 + m] = i0 * ip2_w[m * 2] + i1 * ip2_w[m * 2 + 1];
        }
    }
}

extern "C" void kernel_launch(void* const* d_in, const int* in_sizes, int n_in,
                              void* d_out, int out_size, void* d_ws, size_t ws_size,
                              hipStream_t stream) {
    const float* x     = (const float*)d_in[0];
    const float* w1    = (const float*)d_in[1];
    const float* a1    = (const float*)d_in[2];
    const float* w2    = (const float*)d_in[3];
    const float* a2    = (const float*)d_in[4];
    const float* ip1_w = (const float*)d_in[5];
    const float* ip1_b = (const float*)d_in[6];
    const float* a3    = (const float*)d_in[7];
    const float* ip2_w = (const float*)d_in[8];
    float* out = (float*)d_out;

    char* ws = (char*)d_ws;
    float* wt1   = (float*)(ws);                //   3200 B
    u32*   wt2h  = (u32*)(ws + 4096);           //  51200 B
    float* grm   = (float*)(ws + 131072);       // 2359296 B [256][2][32][12][3]
    float* h1pad = (float*)(ws + 4194304);      // 25.69 MB fp32

    prep_weights<<<52, 512, 0, stream>>>(w1, w2, wt1, wt2h);
    layer1<<<256, 896, 0, stream>>>(x, wt1, a1, h1pad);
    layer2_conv<<<512, 768, 0, stream>>>(h1pad, wt2h, a2, grm);
    pool_fc<<<256, 320, 0, stream>>>(grm, ip1_w, ip1_b, a3, ip2_w, out);
}